// Round 15
// baseline (78.614 us; speedup 1.0000x reference)
//
#include <hip/hip_runtime.h>
#include <stdint.h>

// CandidateFinder: binary-quantize (x>0), exact match on two 32-bit dim
// groups (union), gather first <=64 matching key indices per query, pad -1.
//
// R14 -> R15: unified fused-family model: GPU ~= max(LLC bytes = 0.36*nb us,
// per-CU work), nb = blocks/batch. nb=64 is byte-bound (23us, matches
// R5/R12/R14); R10's nb=16 34us was per-CU bound w/ scalar ingest + 64
// live ballot SGPRs (scratch spill suspect). Never tested: nb=16 + float4
// ingest + small register groups. This round: QPB=128, 64 blocks, ingest
// groups of 4 uint4 loads (16 rows, m[4][4]=32 SGPR only), 8 q/wave scan.
// Model: max(5.8, 3.4+1+2) ~= 6-8us GPU, ONE node, no d_ws.
//
// Pack permutation (from R14, verified absmax=0): ballot bit l of component
// c = (row r0+(l>>4), dim 4*(l&15)+c). Lanes 0-3 assemble rows r0+0..3 via
// sh=16*lane; dims 4s+c with s<=7 stay in group A word, s>=8 in group B —
// a FIXED within-group bit permutation, identical for Q and K -> exact
// equality semantics. Matches emitted in ascending key order via
// ballot+popcount prefix = reference's sort-then-truncate.

#define LSEQ 2048
#define DDIM 64
#define KMAX 64
#define QPB  128  // queries per block -> 16 blocks/batch, 64 total at B=4
#define NW   16   // waves per block (1024 threads)
#define QG   8    // queries per wave

// assemble row (r0 + j)'s sig from 4 component ballots, j = lane (0..3)
__device__ __forceinline__ uint2 asm_sig(
    unsigned long long m0, unsigned long long m1,
    unsigned long long m2, unsigned long long m3, int j) {
    unsigned sh = 16u * j;
    unsigned long long t0 = m0 >> sh, t1 = m1 >> sh,
                       t2 = m2 >> sh, t3 = m3 >> sh;
    unsigned sa = (unsigned)(t0 & 0xFF) | ((unsigned)(t1 & 0xFF) << 8)
                | ((unsigned)(t2 & 0xFF) << 16) | ((unsigned)(t3 & 0xFF) << 24);
    unsigned sb = (unsigned)((t0 >> 8) & 0xFF)
                | ((unsigned)((t1 >> 8) & 0xFF) << 8)
                | ((unsigned)((t2 >> 8) & 0xFF) << 16)
                | ((unsigned)((t3 >> 8) & 0xFF) << 24);
    return make_uint2(sa, sb);
}

__global__ __launch_bounds__(1024) void fused_kernel(
    const float* __restrict__ query, const float* __restrict__ key,
    int* __restrict__ out) {
    __shared__ uint2 ks[LSEQ];          // 16 KB: key sigs (permuted space)
    __shared__ uint2 qs[QPB];           // 1 KB: this block's query sigs

    const int bpb = LSEQ / QPB;         // 16 blocks per batch
    int b    = blockIdx.x / bpb;
    int qblk = blockIdx.x % bpb;
    int lane = threadIdx.x & 63;
    int wave = threadIdx.x >> 6;

    const uint4* kb4 = (const uint4*)(key   + (size_t)b * LSEQ * DDIM);
    const uint4* qb4 = (const uint4*)(query + (size_t)b * LSEQ * DDIM);

    // ---- query pack: 8 rows/wave = 2 branch-free 1KB loads ----
    {
        int qrow0 = wave * QG;                      // local query base
        uint4 qv[2];
#pragma unroll
        for (int i = 0; i < 2; ++i)
            qv[i] = qb4[((size_t)qblk * QPB + qrow0 + i * 4) * 16 + lane];
        unsigned long long qm[2][4];
#pragma unroll
        for (int i = 0; i < 2; ++i) {
            qm[i][0] = __ballot(__uint_as_float(qv[i].x) > 0.0f);
            qm[i][1] = __ballot(__uint_as_float(qv[i].y) > 0.0f);
            qm[i][2] = __ballot(__uint_as_float(qv[i].z) > 0.0f);
            qm[i][3] = __ballot(__uint_as_float(qv[i].w) > 0.0f);
        }
        if (lane < 4) {
#pragma unroll
            for (int i = 0; i < 2; ++i)
                qs[qrow0 + i * 4 + lane] =
                    asm_sig(qm[i][0], qm[i][1], qm[i][2], qm[i][3], lane);
        }
    }

    // ---- key pack: 128 rows/wave, 8 groups of 4 branch-free 1KB loads ----
    for (int g = 0; g < 8; ++g) {
        int r0 = wave * 128 + g * 16;               // 16 rows this group
        uint4 kv[4];
#pragma unroll
        for (int i = 0; i < 4; ++i)                 // 4 loads, one BB
            kv[i] = kb4[(size_t)(r0 + i * 4) * 16 + lane];
        unsigned long long m[4][4];
#pragma unroll
        for (int i = 0; i < 4; ++i) {               // branchless ballots
            m[i][0] = __ballot(__uint_as_float(kv[i].x) > 0.0f);
            m[i][1] = __ballot(__uint_as_float(kv[i].y) > 0.0f);
            m[i][2] = __ballot(__uint_as_float(kv[i].z) > 0.0f);
            m[i][3] = __ballot(__uint_as_float(kv[i].w) > 0.0f);
        }
        if (lane < 4) {                             // ONE exec toggle / group
#pragma unroll
            for (int i = 0; i < 4; ++i)
                ks[r0 + i * 4 + lane] =
                    asm_sig(m[i][0], m[i][1], m[i][2], m[i][3], lane);
        }
    }
    __syncthreads();

    // ---- scan: 8 queries/wave, 16 uint4 LDS loads each (2 keys/lane) ----
    const uint4* kt4 = (const uint4*)ks;
    unsigned long long below = (1ull << lane) - 1ull;
    for (int t = 0; t < QG; ++t) {
        uint2 q = qs[wave * QG + t];                // uniform addr: broadcast
        unsigned qa = q.x, qg = q.y;
        int* ob = out +
            ((size_t)b * LSEQ + (size_t)qblk * QPB + wave * QG + t) * KMAX;

        // fast path: fully branchless, 16 ds_read_b128 back-to-back
        unsigned long long acc = 0;
        int cnt = 0;
#pragma unroll
        for (int i = 0; i < LSEQ / 128; ++i) {      // 16 iters, 128 keys
            uint4 kv = kt4[i * 64 + lane];
            bool mA = (kv.x == qa) | (kv.y == qg);  // key 2*(i*64+lane)
            bool mB = (kv.z == qa) | (kv.w == qg);  // key 2*(i*64+lane)+1
            unsigned long long s;
            s = __ballot(mA); acc |= s; cnt += __popcll(s);
            s = __ballot(mB); acc |= s; cnt += __popcll(s);
        }

        if (acc != 0) {                             // wave-uniform, p~2^-26:
            // exact ordered emit (ascending key idx = sort-then-truncate)
            int c2 = 0;
            for (int c = 0; c < LSEQ / 64; ++c) {
                uint2 kv = ks[c * 64 + lane];
                bool m = (kv.x == qa) || (kv.y == qg);
                unsigned long long mask = __ballot(m);
                if (m) {
                    int pos = c2 + __popcll(mask & below);
                    if (pos < KMAX) ob[pos] = c * 64 + lane;
                }
                c2 += __popcll(mask);
            }
        }
        // pad remaining slots with -1 (64 lanes == KMAX; disjoint vs matches)
        if (lane >= cnt) ob[lane] = -1;
    }
}

extern "C" void kernel_launch(void* const* d_in, const int* in_sizes, int n_in,
                              void* d_out, int out_size, void* d_ws, size_t ws_size,
                              hipStream_t stream) {
    const float* q = (const float*)d_in[0];
    const float* k = (const float*)d_in[1];
    // d_in[2] = head_idx, unused (inputs are already per-head)
    int* out = (int*)d_out;

    int total = in_sizes[0];             // B * L * D
    int B = total / (LSEQ * DDIM);       // = 4

    fused_kernel<<<B * (LSEQ / QPB), 1024, 0, stream>>>(q, k, out);
}

// Round 16
// 72.547 us; speedup vs baseline: 1.0836x; 1.0836x over previous
//
#include <hip/hip_runtime.h>
#include <stdint.h>

// CandidateFinder: binary-quantize (x>0), exact match on two 32-bit dim
// groups (union), gather first <=64 matching key indices per query, pad -1.
//
// R15 -> R16: structural model from 15 rounds: one-node totals = 47.5us
// harness floor + GPU (structural ~0); two-node adds a ~10.6us dependency
// boundary -> 63.1us with ~4.5us GPU. One-node bar: GPU < 15.6us. R14's
// 21.3us at nb=64 blocks/batch fits LLC-byte bound (128MB redundant raw-key
// slab / 6.1TB/s). Untested point nb=32 halves bytes -> predicted 13-15us
// GPU. This kernel = R14 verbatim with QPB 32 -> 64 (128 blocks, 4 q/wave).
//
// Pack permutation (verified absmax=0 in R14/R15): ballot bit l of
// component c = (row r0+(l>>4), dim 4*(l&15)+c). Lanes 0-3 assemble rows
// r0+0..3 via sh=16*lane; dims 4s+c with s<=7 stay in group A word, s>=8
// in group B — a FIXED within-group bit permutation, identical for Q and K
// -> exact equality semantics. Matches emitted in ascending key order via
// ballot+popcount prefix = reference's sort-then-truncate.

#define LSEQ 2048
#define DDIM 64
#define KMAX 64
#define QPB  64   // queries per block -> 32 blocks/batch, 128 total at B=4
#define NW   16   // waves per block (1024 threads)
#define QG   4    // queries per wave (NW * QG == QPB)

// assemble row (r0 + j)'s sig from 4 component ballots, j = lane (0..3)
__device__ __forceinline__ uint2 asm_sig(
    unsigned long long m0, unsigned long long m1,
    unsigned long long m2, unsigned long long m3, int j) {
    unsigned sh = 16u * j;
    unsigned long long t0 = m0 >> sh, t1 = m1 >> sh,
                       t2 = m2 >> sh, t3 = m3 >> sh;
    unsigned sa = (unsigned)(t0 & 0xFF) | ((unsigned)(t1 & 0xFF) << 8)
                | ((unsigned)(t2 & 0xFF) << 16) | ((unsigned)(t3 & 0xFF) << 24);
    unsigned sb = (unsigned)((t0 >> 8) & 0xFF)
                | ((unsigned)((t1 >> 8) & 0xFF) << 8)
                | ((unsigned)((t2 >> 8) & 0xFF) << 16)
                | ((unsigned)((t3 >> 8) & 0xFF) << 24);
    return make_uint2(sa, sb);
}

__global__ __launch_bounds__(1024) void fused_kernel(
    const float* __restrict__ query, const float* __restrict__ key,
    int* __restrict__ out) {
    __shared__ uint2 ks[LSEQ];          // 16 KB: key sigs (permuted space)
    __shared__ uint2 qs[QPB];           // this block's query sigs

    const int bpb = LSEQ / QPB;         // 32 blocks per batch
    int b    = blockIdx.x / bpb;
    int qblk = blockIdx.x % bpb;
    int lane = threadIdx.x & 63;
    int wave = threadIdx.x >> 6;

    const uint4* kb4 = (const uint4*)(key   + (size_t)b * LSEQ * DDIM);
    const uint4* qb4 = (const uint4*)(query + (size_t)b * LSEQ * DDIM);

    // ---- query pack: 4 rows/wave = 1 branch-free 1KB load ----
    {
        int qrow0 = wave * QG;                      // local query base
        uint4 qv = qb4[((size_t)qblk * QPB + qrow0) * 16 + lane];
        unsigned long long qm0 = __ballot(__uint_as_float(qv.x) > 0.0f);
        unsigned long long qm1 = __ballot(__uint_as_float(qv.y) > 0.0f);
        unsigned long long qm2 = __ballot(__uint_as_float(qv.z) > 0.0f);
        unsigned long long qm3 = __ballot(__uint_as_float(qv.w) > 0.0f);
        if (lane < 4)
            qs[qrow0 + lane] = asm_sig(qm0, qm1, qm2, qm3, lane);
    }

    // ---- key pack: 128 rows/wave, 8 groups of 4 branch-free 1KB loads ----
    for (int g = 0; g < 8; ++g) {
        int r0 = wave * 128 + g * 16;               // 16 rows this group
        uint4 kv[4];
#pragma unroll
        for (int i = 0; i < 4; ++i)                 // 4 loads, one BB
            kv[i] = kb4[(size_t)(r0 + i * 4) * 16 + lane];
        unsigned long long m[4][4];
#pragma unroll
        for (int i = 0; i < 4; ++i) {               // branchless ballots
            m[i][0] = __ballot(__uint_as_float(kv[i].x) > 0.0f);
            m[i][1] = __ballot(__uint_as_float(kv[i].y) > 0.0f);
            m[i][2] = __ballot(__uint_as_float(kv[i].z) > 0.0f);
            m[i][3] = __ballot(__uint_as_float(kv[i].w) > 0.0f);
        }
        if (lane < 4) {                             // ONE exec toggle / group
#pragma unroll
            for (int i = 0; i < 4; ++i)
                ks[r0 + i * 4 + lane] =
                    asm_sig(m[i][0], m[i][1], m[i][2], m[i][3], lane);
        }
    }
    __syncthreads();

    // ---- scan: 4 queries/wave, 16 uint4 LDS loads each (2 keys/lane) ----
    const uint4* kt4 = (const uint4*)ks;
    unsigned long long below = (1ull << lane) - 1ull;
    for (int t = 0; t < QG; ++t) {
        uint2 q = qs[wave * QG + t];                // uniform addr: broadcast
        unsigned qa = q.x, qg = q.y;
        int* ob = out +
            ((size_t)b * LSEQ + (size_t)qblk * QPB + wave * QG + t) * KMAX;

        // fast path: fully branchless, 16 ds_read_b128 back-to-back
        unsigned long long acc = 0;
        int cnt = 0;
#pragma unroll
        for (int i = 0; i < LSEQ / 128; ++i) {      // 16 iters, 128 keys
            uint4 kv = kt4[i * 64 + lane];
            bool mA = (kv.x == qa) | (kv.y == qg);  // key 2*(i*64+lane)
            bool mB = (kv.z == qa) | (kv.w == qg);  // key 2*(i*64+lane)+1
            unsigned long long s;
            s = __ballot(mA); acc |= s; cnt += __popcll(s);
            s = __ballot(mB); acc |= s; cnt += __popcll(s);
        }

        if (acc != 0) {                             // wave-uniform, p~2^-26:
            // exact ordered emit (ascending key idx = sort-then-truncate)
            int c2 = 0;
            for (int c = 0; c < LSEQ / 64; ++c) {
                uint2 kv = ks[c * 64 + lane];
                bool m = (kv.x == qa) || (kv.y == qg);
                unsigned long long mask = __ballot(m);
                if (m) {
                    int pos = c2 + __popcll(mask & below);
                    if (pos < KMAX) ob[pos] = c * 64 + lane;
                }
                c2 += __popcll(mask);
            }
        }
        // pad remaining slots with -1 (64 lanes == KMAX; disjoint vs matches)
        if (lane >= cnt) ob[lane] = -1;
    }
}

extern "C" void kernel_launch(void* const* d_in, const int* in_sizes, int n_in,
                              void* d_out, int out_size, void* d_ws, size_t ws_size,
                              hipStream_t stream) {
    const float* q = (const float*)d_in[0];
    const float* k = (const float*)d_in[1];
    // d_in[2] = head_idx, unused (inputs are already per-head)
    int* out = (int*)d_out;

    int total = in_sizes[0];             // B * L * D
    int B = total / (LSEQ * DDIM);       // = 4

    fused_kernel<<<B * (LSEQ / QPB), 1024, 0, stream>>>(q, k, out);
}